// Round 1
// baseline (345.240 us; speedup 1.0000x reference)
//
#include <hip/hip_runtime.h>
#include <cmath>

#define HH 96
#define WW 96
#define NPIX (HH * WW)
#define COEF 5.0f
#define BIGV 1.0e9f

// Kernel 1: per-pixel flat_ computation + init dmax slot.
__global__ void k_flat(const float* __restrict__ img,
                       const float* __restrict__ thre,
                       const float* __restrict__ add,
                       float* __restrict__ flat_out,   // ws[0..NPIX)
                       float* __restrict__ dmax_slot)  // ws[NPIX]
{
    int t = blockIdx.x * blockDim.x + threadIdx.x;
    if (t == 0) *dmax_slot = 0.0f;  // int bits of 0.0f are 0
    if (t >= NPIX) return;
    int i = t / WW, j = t % WW;
    float v  = img[t];
    float th = thre[t];
    bool high = (v >= th);

    // 5x5 local max over "low" pixels (img < thre); 0 if none in window
    float mx = -BIGV;
    for (int di = -2; di <= 2; ++di) {
        int ni = i + di;
        if (ni < 0 || ni >= HH) continue;
        for (int dj = -2; dj <= 2; ++dj) {
            int nj = j + dj;
            if (nj < 0 || nj >= WW) continue;
            int n = ni * WW + nj;
            float nv = img[n];
            if (nv < thre[n]) mx = fmaxf(mx, nv);
        }
    }
    float maxlim = (mx <= -BIGV * 0.5f) ? 0.0f : mx;

    // 3x3 local min over "high" pixels (img >= thre); 0 if none in window
    float mn = BIGV;
    for (int di = -1; di <= 1; ++di) {
        int ni = i + di;
        if (ni < 0 || ni >= HH) continue;
        for (int dj = -1; dj <= 1; ++dj) {
            int nj = j + dj;
            if (nj < 0 || nj >= WW) continue;
            int n = ni * WW + nj;
            float nv = img[n];
            if (nv >= thre[n]) mn = fminf(mn, nv);
        }
    }
    float minlim = (mn >= BIGV * 0.5f) ? 0.0f : mn;

    float img_high = high ? v : 0.0f;
    float img_low  = high ? 0.0f : v;
    // NOTE: reference applies these transforms to ALL pixels (img_high=0 on
    // low pixels still yields -minlim/(1-minlim+eps)), so no masking here.
    float ih = (img_high - minlim) / (1.0f - minlim + 1e-11f);
    float il = img_low / (maxlim + 1e-11f);
    flat_out[t] = ih + il + (high ? add[t] : 0.0f);
}

// Kernel 2: max over all edges of |flat_[r] - flat_[c]| (undirected == directed for abs)
__global__ void k_dmax(const float* __restrict__ flat_, float* dmax_slot)
{
    int t = blockIdx.x * blockDim.x + threadIdx.x;
    float d = 0.0f;
    if (t < NPIX) {
        int i = t / WW, j = t % WW;
        float fc = flat_[t];
        if (j + 1 < WW) d = fmaxf(d, fabsf(fc - flat_[t + 1]));
        if (i + 1 < HH) d = fmaxf(d, fabsf(fc - flat_[t + WW]));
    }
    // wave-64 shuffle reduce max
    for (int off = 32; off > 0; off >>= 1)
        d = fmaxf(d, __shfl_down(d, off, 64));
    if ((threadIdx.x & 63) == 0)
        atomicMax((int*)dmax_slot, __float_as_int(d));  // d >= 0: int-bit order matches
}

// Kernel 3: zero-fill the whole NxN output (re-poisoned to 0xAA each call)
__global__ void k_zero(float4* __restrict__ out, long n4)
{
    long t = (long)blockIdx.x * blockDim.x + threadIdx.x;
    if (t < n4) out[t] = make_float4(0.0f, 0.0f, 0.0f, 0.0f);
}

// Kernel 4: scatter nonzeros. out[i, nb] = total_e / row_sum_i.
// (The total.max() normalization cancels exactly between weights and row_sum.)
__global__ void k_scatter(const float* __restrict__ flat_,
                          const float* __restrict__ dmax_slot,
                          float* __restrict__ out)
{
    int t = blockIdx.x * blockDim.x + threadIdx.x;
    if (t >= NPIX) return;
    int i = t / WW, j = t % WW;
    float fc = flat_[t];
    float inv_d = 1.0f / (*dmax_slot + 1e-11f);
    const float es = expf(-COEF);  // spatial term: distance is always exactly 1

    int   nbr[4];
    float tot[4];
    int   cnt = 0;
    float row_sum = 0.0f;
    const int  off[4] = {-WW, WW, -1, 1};
    const bool ok[4]  = { i > 0, i < HH - 1, j > 0, j < WW - 1 };
    for (int k = 0; k < 4; ++k) {
        if (!ok[k]) continue;
        int n = t + off[k];
        float d = fabsf(fc - flat_[n]);
        float total = es + expf(-COEF * d * inv_d);
        nbr[cnt] = n;
        tot[cnt] = total;
        ++cnt;
        row_sum += total;
    }
    float inv_rs = 1.0f / row_sum;  // row_sum >= 2*exp(-5) > 0 always
    size_t base = (size_t)t * NPIX;
    for (int k = 0; k < cnt; ++k)
        out[base + nbr[k]] = tot[k] * inv_rs;
}

extern "C" void kernel_launch(void* const* d_in, const int* in_sizes, int n_in,
                              void* d_out, int out_size, void* d_ws, size_t ws_size,
                              hipStream_t stream)
{
    const float* img  = (const float*)d_in[0];
    const float* thre = (const float*)d_in[1];
    const float* add  = (const float*)d_in[2];
    float* out = (float*)d_out;
    float* ws  = (float*)d_ws;

    float* flat_ = ws;           // NPIX floats
    float* dmax  = ws + NPIX;    // 1 float

    const int tpb = 256;
    const int pix_blocks = (NPIX + tpb - 1) / tpb;

    k_flat<<<pix_blocks, tpb, 0, stream>>>(img, thre, add, flat_, dmax);
    k_dmax<<<pix_blocks, tpb, 0, stream>>>(flat_, dmax);

    long n4 = (long)out_size / 4;  // out_size = NPIX*NPIX, divisible by 4
    int zero_blocks = (int)((n4 + tpb - 1) / tpb);
    k_zero<<<zero_blocks, tpb, 0, stream>>>((float4*)out, n4);

    k_scatter<<<pix_blocks, tpb, 0, stream>>>(flat_, dmax, out);
}